// Round 10
// baseline (180.144 us; speedup 1.0000x reference)
//
#include <hip/hip_runtime.h>

#define HH 512
#define WW 640
#define HP 384
#define WP 512
#define PAD 64
#define NF 16
#define HW (HH*WW)
#define FRDW (HP*WP)            // dwords per y_pred frame
#define NPX 256                 // pixels per block (merged kloc: 1 thread/pixel)
#define NPH 8                   // phases (2 frames each)
#define NBLK (HW/NPX)           // 1280 blocks

typedef float vf2 __attribute__((ext_vector_type(2)));
typedef float vf4 __attribute__((ext_vector_type(4)));

__device__ __forceinline__ float ntload(const float* p) {
    return __builtin_nontemporal_load(p);
}

// 8B load at 4B alignment — single global_load_dwordx2 on gfx950.
__device__ __forceinline__ vf2 ld2u(const float* __restrict__ p) {
    vf2 r;
    __builtin_memcpy(&r, p, sizeof(r));
    return r;
}
// aligned 16B load
__device__ __forceinline__ vf4 ld4(const float* __restrict__ p) {
    return *reinterpret_cast<const vf4*>(p);
}

// bilinear sample of padded y_pred1[f] at raw grid coords (Cy, Cx).
// Two x-taps fused into ONE dwordx2 gather; ix clamped to [0, WP-2] so the 8B
// access stays in-frame; d-selects reproduce reference OOB masking bit-exactly.
__device__ __forceinline__ float bsample(const float* __restrict__ yp, int f, float Cy, float Cx) {
    float gy = (Cy - 256.0f) / 256.0f;
    float gx = (Cx - 320.0f) / 320.0f;
    float y = ((gy + 1.0f) * 512.0f - 1.0f) * 0.5f;
    float x = ((gx + 1.0f) * 640.0f - 1.0f) * 0.5f;
    float y0f = floorf(y), x0f = floorf(x);
    float wy1 = y - y0f, wx1 = x - x0f;
    float wy0 = 1.0f - wy1, wx0 = 1.0f - wx1;
    int iy0 = (int)y0f - PAD;              // pad-local coords
    int ix  = (int)x0f - PAD;
    int ixc = min(max(ix, 0), WP - 2);     // [ixc, ixc+1] always in-row
    int d   = ix - ixc;                    // 0 aligned; ±1 edge; else fully OOB

    const float* base = yp + (size_t)f * FRDW + ixc;
    float r0 = 0.f, r1 = 0.f;
    if ((unsigned)iy0 < HP) {
        vf2 v = ld2u(base + (size_t)iy0 * WP);
        float v0 = (d == 0) ? v.x : ((d == 1)  ? v.y : 0.f);
        float v1 = (d == 0) ? v.y : ((d == -1) ? v.x : 0.f);
        r0 = wx0 * v0 + wx1 * v1;
    }
    if ((unsigned)(iy0 + 1) < HP) {
        vf2 v = ld2u(base + (size_t)(iy0 + 1) * WP);
        float v0 = (d == 0) ? v.x : ((d == 1)  ? v.y : 0.f);
        float v1 = (d == 0) ? v.y : ((d == -1) ? v.x : 0.f);
        r1 = wx0 * v0 + wx1 * v1;
    }
    return wy0 * r0 + wy1 * r1;
}

__device__ __forceinline__ void coef(const float* __restrict__ inp7,
                                     const float* __restrict__ inp77,
                                     int k, float& a, float& b, float& c) {
    if (k == 0)      { a = inp77[0] + 1.0f;  b = inp77[3];     c = inp77[6];     }
    else if (k <= 15){ a = inp7[k-1] + 1.0f; b = inp7[45+k-1]; c = inp7[90+k-1]; }
    else             { a = 1.0f;             b = 0.0f;         c = 0.0f;         }
}

// Merged-kloc structure: 1 thread = 1 pixel, both frames of each phase.
// The per-phase dependency set (frames {2g-1, 2g, 2g+1}) is IDENTICAL to the
// R3 equilibrium — no L2-window widening (R2/R4/R6/R7 lesson) — while phase
// epochs per CU halve (40 vs 80) and per-thread loads-in-flight double (~18).
// C/Cb lines live in registers (LDS staging at 256px would cost 64KB → 2
// blocks/CU); phase g uses cl[g]/cbl[g], static after full unroll.
__global__ __launch_bounds__(256, 4) void verloss_main(
    const float* __restrict__ y_pred,   // (15, 384, 512)
    const float* __restrict__ inp1,     // (2, H, W)
    const float* __restrict__ inp2,     // (32, H, W)
    const float* __restrict__ inp2b,    // (32, H, W)
    const float* __restrict__ inp7,     // (135)
    const float* __restrict__ inp6,     // (384, 512)
    const float* __restrict__ inp77,    // (9)
    const float* __restrict__ C,        // (H, W, 32)
    const float* __restrict__ Cb,       // (H, W, 32)
    double* __restrict__ partial)
{
    __shared__ double sdata[4];

    const int tid = threadIdx.x;
    const int p   = blockIdx.x * NPX + tid;    // global pixel

    // ---- upfront: this pixel's C/Cb lines into registers.
    // Plain (non-nt) dwordx4: 8 consecutive 16B chunks of one 128B line per
    // lane — L1 merges; each line fetched once. (nt would bypass caching and
    // refetch the line 8x.) cl[g] = {Cy(2g),Cx(2g),Cy(2g+1),Cx(2g+1)}.
    vf4 cl[NPH], cbl[NPH];
    {
        const float* cp  = C  + (size_t)p * 32;
        const float* cbp = Cb + (size_t)p * 32;
        #pragma unroll
        for (int j = 0; j < NPH; ++j) {
            cl [j] = ld4(cp  + 4 * j);
            cbl[j] = ld4(cbp + 4 * j);
        }
    }

    // ---- per-pixel invariants
    int y = p / WW, x = p - y * WW;
    int iy = y - PAD, ix = x - PAD;
    bool inpad = ((unsigned)iy < HP) && ((unsigned)ix < WP);
    int padoff = iy * WP + ix;                 // valid only if inpad
    float A = inp1[HW + p];                    // inp1[0,1]
    float B = inp1[p];                         // inp1[0,0]

    // Two float accumulators (even-k / odd-k) reproduce the previous
    // per-thread (kloc) summation order bit-exactly; merged in double below.
    float accE = 0.f, accO = 0.f;
    float ypm = inpad ? inp6[padoff] : 0.f;    // prev(k=0); thereafter y_pred[2g-1]

    #pragma unroll
    for (int g = 0; g < NPH; ++g) {
        const int k0 = 2 * g, k1 = 2 * g + 1;

        // uniform coefficient triples for k0, k0+1(=k1), k1+1
        float a0, b0, c0, a1, b1, c1, a2, b2, c2;
        coef(inp7, inp77, k0,     a0, b0, c0);
        coef(inp7, inp77, k0 + 1, a1, b1, c1);
        coef(inp7, inp77, k1 + 1, a2, b2, c2);

        // direct terms: y_pred[2g] shared (nxt of k0 == prev of k1);
        // y_pred[2g+1] carried into next phase as its prev.
        float yp0 = inpad ? y_pred[(size_t)k0 * FRDW + padoff] : 0.f;
        float yp1 = (g < NPH - 1 && inpad) ? y_pred[(size_t)k1 * FRDW + padoff] : 0.f;

        // warped terms — 4 bilinear gathers, frames {2g-1, 2g, 2g+1} only
        float w5_0 = bsample(y_pred, k0, cl[g].x, cl[g].y);                  // frame 2g
        float w5_1 = (g < NPH - 1) ? bsample(y_pred, k1, cl[g].z, cl[g].w) : 0.f; // 2g+1
        float w6_0 = (g >= 1) ? bsample(y_pred, k0 - 1, cbl[g].x, cbl[g].y) : 0.f; // 2g-1
        float w6_1 = bsample(y_pred, k1 - 1, cbl[g].z, cbl[g].w);            // frame 2g

        // touch-once streams — non-temporal, fully coalesced
        float i2_0hi = ntload(inp2  + (size_t)(2*k0+1)*HW + p);
        float i2_0lo = ntload(inp2  + (size_t)(2*k0  )*HW + p);
        float ib_0hi = ntload(inp2b + (size_t)(2*k0+1)*HW + p);
        float ib_0lo = ntload(inp2b + (size_t)(2*k0  )*HW + p);
        float i2_1hi = ntload(inp2  + (size_t)(2*k1+1)*HW + p);
        float i2_1lo = ntload(inp2  + (size_t)(2*k1  )*HW + p);
        float ib_1hi = ntload(inp2b + (size_t)(2*k1+1)*HW + p);
        float ib_1lo = ntload(inp2b + (size_t)(2*k1  )*HW + p);

        // k0 (even) terms — expressions verbatim from R3 for bit-identity
        float d0 = a0*A + b0*B + c0 + ypm - (a1*i2_0hi + b1*i2_0lo + c1 + w5_0);
        float d1 = a0*ib_0hi + b0*ib_0lo + c0 + w6_0 - (a1*A + b1*B + c1 + yp0);
        accE += d0*d0 + d1*d1;
        // k1 (odd) terms
        float d2 = a1*A + b1*B + c1 + yp0 - (a2*i2_1hi + b2*i2_1lo + c2 + w5_1);
        float d3 = a1*ib_1hi + b1*ib_1lo + c1 + w6_1 - (a2*A + b2*B + c2 + yp1);
        accO += d2*d2 + d3*d3;

        ypm = yp1;

        if (g < NPH - 1) {
            // Phase-lock WITHOUT vmcnt drain (no LDS crosses this barrier);
            // sched_barrier pins next phase's gathers below it (R4 lesson).
            __builtin_amdgcn_s_barrier();
            __builtin_amdgcn_sched_barrier(0);
        }
    }

    // ---- block reduction in double (accE/accO merged here, as kloc pairs were)
    double v = (double)accE + (double)accO;
    #pragma unroll
    for (int off = 32; off > 0; off >>= 1) v += __shfl_down(v, off, 64);
    int wid = tid >> 6, lane = tid & 63;
    if (lane == 0) sdata[wid] = v;
    __syncthreads();
    if (tid == 0)
        partial[blockIdx.x] = sdata[0] + sdata[1] + sdata[2] + sdata[3];
}

__global__ __launch_bounds__(1024) void verloss_finalize(
    const double* __restrict__ partial, int n, float* __restrict__ out)
{
    double v = 0.0;
    for (int i = threadIdx.x; i < n; i += 1024) v += partial[i];
    #pragma unroll
    for (int off = 32; off > 0; off >>= 1) v += __shfl_down(v, off, 64);
    __shared__ double sdata[16];
    int wid = threadIdx.x >> 6, lane = threadIdx.x & 63;
    if (lane == 0) sdata[wid] = v;
    __syncthreads();
    if (threadIdx.x == 0) {
        double s = 0.0;
        #pragma unroll
        for (int i = 0; i < 16; ++i) s += sdata[i];
        out[0] = (float)(s * (0.5 / ((double)NF * HW)));
    }
}

extern "C" void kernel_launch(void* const* d_in, const int* in_sizes, int n_in,
                              void* d_out, int out_size, void* d_ws, size_t ws_size,
                              hipStream_t stream) {
    const float* y_pred = (const float*)d_in[0];
    const float* inp1   = (const float*)d_in[1];
    const float* inp2   = (const float*)d_in[2];
    const float* inp2b  = (const float*)d_in[3];
    const float* inp7   = (const float*)d_in[4];
    const float* inp6   = (const float*)d_in[5];
    const float* inp77  = (const float*)d_in[6];
    const float* C      = (const float*)d_in[9];
    const float* Cb     = (const float*)d_in[10];
    float* out = (float*)d_out;
    double* partial = (double*)d_ws;

    verloss_main<<<NBLK, 256, 0, stream>>>(y_pred, inp1, inp2, inp2b, inp7,
                                           inp6, inp77, C, Cb, partial);
    verloss_finalize<<<1, 1024, 0, stream>>>(partial, NBLK, out);
}

// Round 11
// 153.300 us; speedup vs baseline: 1.1751x; 1.1751x over previous
//
#include <hip/hip_runtime.h>

#define HH 512
#define WW 640
#define HP 384
#define WP 512
#define PAD 64
#define NF 16
#define HW (HH*WW)
#define FRDW (HP*WP)            // dwords per y_pred frame
#define PXB 128                 // pixels per block
#define NTH 512                 // threads: pixel × role × kloc
#define NPH 8                   // phases (2 frames each)
#define NBLK (HW/PXB)           // 2560 blocks
#define CSTR 34                 // LDS stride (floats) per pixel: 32 + pad

typedef float vf2 __attribute__((ext_vector_type(2)));

__device__ __forceinline__ float ntload(const float* p) {
    return __builtin_nontemporal_load(p);
}
__device__ __forceinline__ vf2 ntload2(const float* p) {
    return __builtin_nontemporal_load(reinterpret_cast<const vf2*>(p));
}

// 8B load at 4B alignment — single global_load_dwordx2 on gfx950.
__device__ __forceinline__ vf2 ld2u(const float* __restrict__ p) {
    vf2 r;
    __builtin_memcpy(&r, p, sizeof(r));
    return r;
}

// bilinear sample of padded y_pred1[f] at raw grid coords (Cy, Cx).
// Two x-taps fused into ONE dwordx2 gather; ix clamped to [0, WP-2] so the 8B
// access stays in-frame; d-selects reproduce reference OOB masking bit-exactly.
__device__ __forceinline__ float bsample(const float* __restrict__ yp, int f, float Cy, float Cx) {
    float gy = (Cy - 256.0f) / 256.0f;
    float gx = (Cx - 320.0f) / 320.0f;
    float y = ((gy + 1.0f) * 512.0f - 1.0f) * 0.5f;
    float x = ((gx + 1.0f) * 640.0f - 1.0f) * 0.5f;
    float y0f = floorf(y), x0f = floorf(x);
    float wy1 = y - y0f, wx1 = x - x0f;
    float wy0 = 1.0f - wy1, wx0 = 1.0f - wx1;
    int iy0 = (int)y0f - PAD;              // pad-local coords
    int ix  = (int)x0f - PAD;
    int ixc = min(max(ix, 0), WP - 2);     // [ixc, ixc+1] always in-row
    int d   = ix - ixc;                    // 0 aligned; ±1 edge; else fully OOB

    const float* base = yp + (size_t)f * FRDW + ixc;
    float r0 = 0.f, r1 = 0.f;
    if ((unsigned)iy0 < HP) {
        vf2 v = ld2u(base + (size_t)iy0 * WP);
        float v0 = (d == 0) ? v.x : ((d == 1)  ? v.y : 0.f);
        float v1 = (d == 0) ? v.y : ((d == -1) ? v.x : 0.f);
        r0 = wx0 * v0 + wx1 * v1;
    }
    if ((unsigned)(iy0 + 1) < HP) {
        vf2 v = ld2u(base + (size_t)(iy0 + 1) * WP);
        float v0 = (d == 0) ? v.x : ((d == 1)  ? v.y : 0.f);
        float v1 = (d == 0) ? v.y : ((d == -1) ? v.x : 0.f);
        r1 = wx0 * v0 + wx1 * v1;
    }
    return wy0 * r0 + wy1 * r1;
}

__device__ __forceinline__ void coef(const float* __restrict__ inp7,
                                     const float* __restrict__ inp77,
                                     int k, float& a, float& b, float& c) {
    if (k == 0)      { a = inp77[0] + 1.0f;  b = inp77[3];     c = inp77[6];     }
    else if (k <= 15){ a = inp7[k-1] + 1.0f; b = inp7[45+k-1]; c = inp7[90+k-1]; }
    else             { a = 1.0f;             b = 0.0f;         c = 0.0f;         }
}

// Role-split structure: same 128 pixels/block, same 2560 blocks, same phase
// lock, same per-phase frame window {2g-1,2g,2g+1} — the L2 equilibrium
// (R2/R4/R6/R7) is untouched. What changes: the two INDEPENDENT squared terms
// d0 (prev, inp2, w5) and d1 (nxt, inp2b, w6) go to separate threads →
// 512 threads/block → waves/CU 16 → 32 at the same footprint. d1 rejoins d0's
// thread via shfl_xor(2) and is accumulated with R3's verbatim expression.
// launch_bounds(512,4) = VGPR cap 128, NOT forced-8 (R5 spill lesson);
// R3's full work used 52 VGPR under this cap, halved work lands <=64 →
// hardware reaches 4 blocks/CU = 32 waves organically.
__global__ __launch_bounds__(NTH, 4) void verloss_main(
    const float* __restrict__ y_pred,   // (15, 384, 512)
    const float* __restrict__ inp1,     // (2, H, W)
    const float* __restrict__ inp2,     // (32, H, W)
    const float* __restrict__ inp2b,    // (32, H, W)
    const float* __restrict__ inp7,     // (135)
    const float* __restrict__ inp6,     // (384, 512)
    const float* __restrict__ inp77,    // (9)
    const float* __restrict__ C,        // (H, W, 32)
    const float* __restrict__ Cb,       // (H, W, 32)
    double* __restrict__ partial)
{
    __shared__ float sC [PXB * CSTR];
    __shared__ float sCb[PXB * CSTR];
    __shared__ double sdata[8];

    const int tid  = threadIdx.x;
    const int kloc = tid & 1;                  // k parity
    const int role = (tid >> 1) & 1;           // 0: d0-side (w5), 1: d1-side (w6)
    const int pxl  = tid >> 2;                 // local pixel 0..127
    const int p    = blockIdx.x * PXB + pxl;   // global pixel

    // ---- stage this block's C/Cb lines into LDS (coalesced, nontemporal)
    {
        const float* gC  = C  + (size_t)blockIdx.x * PXB * 32;
        const float* gCb = Cb + (size_t)blockIdx.x * PXB * 32;
        #pragma unroll
        for (int i = 0; i < 4; ++i) {
            int f2 = tid + i * NTH;            // float2 index 0..2047
            int spx = f2 >> 4, sj = f2 & 15;   // pixel, float2-within-line
            vf2 v  = ntload2(gC  + 2 * f2);
            vf2 vb = ntload2(gCb + 2 * f2);
            *reinterpret_cast<vf2*>(&sC [spx * CSTR + 2 * sj]) = v;
            *reinterpret_cast<vf2*>(&sCb[spx * CSTR + 2 * sj]) = vb;
        }
    }

    // ---- per-pixel invariants
    int y = p / WW, x = p - y * WW;
    int iy = y - PAD, ix = x - PAD;
    bool inpad = ((unsigned)iy < HP) && ((unsigned)ix < WP);
    int padoff = iy * WP + ix;                 // valid only if inpad
    float A = inp1[HW + p];                    // inp1[0,1]
    float B = inp1[p];                         // inp1[0,0]

    float acc = 0.f;
    __syncthreads();                           // staging → reads

    // Phase-locked loop, structure identical to R3 (131 µs proven).
    for (int g = 0; g < NPH; ++g) {
        int k = 2 * g + kloc;                  // frame 0..15

        float ak, bk, ck, an, bn, cn;
        coef(inp7, inp77, k,     ak, bk, ck);
        coef(inp7, inp77, k + 1, an, bn, cn);

        // unified direct term: role0 → prev (inp6 or frame k-1); role1 → nxt (frame k)
        const float* dbase = role ? y_pred + (size_t)k * FRDW
                                  : (k == 0 ? inp6 : y_pred + (size_t)(k-1) * FRDW);
        bool dvalid = inpad && (!role || k < NF - 1);
        float dterm = dvalid ? dbase[padoff] : 0.f;

        // unified gather: role0 → w5 = sample(frame k, sC); role1 → w6 = sample(frame k-1, sCb)
        const float* sbase = role ? sCb : sC;
        vf2 gg = *reinterpret_cast<const vf2*>(sbase + pxl * CSTR + 2 * k);
        bool wvalid = role ? (k >= 1) : (k < NF - 1);
        float w = 0.f;
        if (wvalid) w = bsample(y_pred, k - role, gg.x, gg.y);

        // unified streams: role0 → inp2 pair; role1 → inp2b pair (touch-once, nt)
        const float* sp = role ? inp2b : inp2;
        float shi = ntload(sp + (size_t)(2*k+1)*HW + p);
        float slo = ntload(sp + (size_t)(2*k  )*HW + p);

        // difference terms — expression shapes verbatim from R3 for bit-identity
        float t0 = ak*A + bk*B + ck + dterm - (an*shi + bn*slo + cn + w);
        float t1 = ak*shi + bk*slo + ck + w - (an*A + bn*B + cn + dterm);
        float dval = role ? t1 : t0;

        // pair d0 with its d1 (same pixel, same k: lane ^ 2) and accumulate
        // exactly as R3 did: acc += d0*d0 + d1*d1 on the role0 thread.
        float dsw = __shfl_xor(dval, 2, 64);
        if (!role) {
            float d0 = dval, d1 = dsw;
            acc += d0*d0 + d1*d1;
        }

        if (g < NPH - 1) __syncthreads();      // keep block phase-locked
    }

    // ---- block reduction in double
    double v = (double)acc;
    #pragma unroll
    for (int off = 32; off > 0; off >>= 1) v += __shfl_down(v, off, 64);
    int wid = tid >> 6, lane = tid & 63;
    if (lane == 0) sdata[wid] = v;
    __syncthreads();
    if (tid == 0) {
        double s = 0.0;
        #pragma unroll
        for (int i = 0; i < 8; ++i) s += sdata[i];
        partial[blockIdx.x] = s;
    }
}

__global__ __launch_bounds__(1024) void verloss_finalize(
    const double* __restrict__ partial, int n, float* __restrict__ out)
{
    double v = 0.0;
    for (int i = threadIdx.x; i < n; i += 1024) v += partial[i];
    #pragma unroll
    for (int off = 32; off > 0; off >>= 1) v += __shfl_down(v, off, 64);
    __shared__ double sdata[16];
    int wid = threadIdx.x >> 6, lane = threadIdx.x & 63;
    if (lane == 0) sdata[wid] = v;
    __syncthreads();
    if (threadIdx.x == 0) {
        double s = 0.0;
        #pragma unroll
        for (int i = 0; i < 16; ++i) s += sdata[i];
        out[0] = (float)(s * (0.5 / ((double)NF * HW)));
    }
}

extern "C" void kernel_launch(void* const* d_in, const int* in_sizes, int n_in,
                              void* d_out, int out_size, void* d_ws, size_t ws_size,
                              hipStream_t stream) {
    const float* y_pred = (const float*)d_in[0];
    const float* inp1   = (const float*)d_in[1];
    const float* inp2   = (const float*)d_in[2];
    const float* inp2b  = (const float*)d_in[3];
    const float* inp7   = (const float*)d_in[4];
    const float* inp6   = (const float*)d_in[5];
    const float* inp77  = (const float*)d_in[6];
    const float* C      = (const float*)d_in[9];
    const float* Cb     = (const float*)d_in[10];
    float* out = (float*)d_out;
    double* partial = (double*)d_ws;

    verloss_main<<<NBLK, NTH, 0, stream>>>(y_pred, inp1, inp2, inp2b, inp7,
                                           inp6, inp77, C, Cb, partial);
    verloss_finalize<<<1, 1024, 0, stream>>>(partial, NBLK, out);
}